// Round 2
// baseline (449.876 us; speedup 1.0000x reference)
//
#include <hip/hip_runtime.h>

typedef unsigned short ushort_t;
typedef __attribute__((ext_vector_type(8))) short bf16x8;
typedef __attribute__((ext_vector_type(4))) float f32x4;

#define NPOS 16384   // H*W
#define CIN 128
#define O3  384
#define HID 128
#define GA  64       // kernel A grid.x
#define TA  4        // position tiles (of 64) per A block; GA*TA = 256

__device__ inline float b2f(ushort_t u) {
    union { unsigned int i; float f; } z; z.i = ((unsigned int)u) << 16; return z.f;
}
__device__ inline ushort_t f2b(float f) {
    union { float f; unsigned int u; } x; x.f = f;
    unsigned int lsb = (x.u >> 16) & 1u;
    unsigned int r = x.u + 0x7fffu + lsb;
    return (ushort_t)(r >> 16);
}

// ---------------- Kernel 0: one-time fp32 -> bf16 conversion of w_qkv ----------------
__global__ __launch_bounds__(256) void k_cvt(const float* __restrict__ wq,
                                             ushort_t* __restrict__ wq_bf) {
    int i = blockIdx.x * 256 + threadIdx.x;   // 0 .. 49151
    wq_bf[i] = f2b(wq[i]);
}

// Legacy staging (fallback path): (128 ch x 64 pos) fp32 tile -> bf16 LDS [pos][ch(136)]
__device__ inline void stage_x64(const float* __restrict__ x, int t, ushort_t (*xt)[136]) {
    int q4 = t & 15;          // position quad 0..15
    int ch0 = t >> 4;         // 0..15
    const float* xp = x + q4 * 4;
#pragma unroll
    for (int it = 0; it < 8; ++it) {
        int c = it * 16 + ch0;
        float4 v = *(const float4*)(xp + (size_t)c * NPOS);
        xt[q4 * 4 + 0][c] = f2b(v.x);
        xt[q4 * 4 + 1][c] = f2b(v.y);
        xt[q4 * 4 + 2][c] = f2b(v.z);
        xt[q4 * 4 + 3][c] = f2b(v.w);
    }
}

// =================================================================================
// NEW PATH: atomic-free partials + q~ produced in pass A (single fp32 read of x)
// =================================================================================

// ---------------- Kernel A2: q/k/v GEMM; q softmax -> q~ (bf16, swizzled, direct global);
//                  exp(k)&v -> ctx/kexp register accumulation over TA tiles -> partials
__global__ __launch_bounds__(256) void k_ctxsum2(const float* __restrict__ x,
                                                 const ushort_t* __restrict__ wq,
                                                 float* __restrict__ kexp_part,
                                                 float* __restrict__ ctx_part,
                                                 ushort_t* __restrict__ qt) {
    __shared__ __align__(16) ushort_t xt[64][136];   // x tile (bf16, [pos][ch])
    __shared__ ushort_t kb[4][32][40];   // per-wave exp(k) transpose: [d][pos]
    __shared__ ushort_t vb[4][32][40];   // per-wave v transpose
    int t = threadIdx.x, b = blockIdx.y, bx = blockIdx.x;
    int w = t >> 6, l = t & 63, lr = l & 15, lq = l >> 4;

    // hoisted weight fragments (reused across TA tiles x 2 chunks)
    bf16x8 qa[2][4], ka[2][4], va[2][4];
#pragma unroll
    for (int g = 0; g < 2; ++g)
#pragma unroll
        for (int kk = 0; kk < 4; ++kk) {
            qa[g][kk] = *(const bf16x8*)(wq + (size_t)(      w * 32 + g * 16 + lr) * CIN + kk * 32 + lq * 8);
            ka[g][kk] = *(const bf16x8*)(wq + (size_t)(128 + w * 32 + g * 16 + lr) * CIN + kk * 32 + lq * 8);
            va[g][kk] = *(const bf16x8*)(wq + (size_t)(256 + w * 32 + g * 16 + lr) * CIN + kk * 32 + lq * 8);
        }

    f32x4 cacc[2][2];
#pragma unroll
    for (int mt = 0; mt < 2; ++mt)
#pragma unroll
        for (int nt = 0; nt < 2; ++nt) cacc[mt][nt] = (f32x4){0.f, 0.f, 0.f, 0.f};
    float sacc[2][4];
#pragma unroll
    for (int g = 0; g < 2; ++g)
#pragma unroll
        for (int r = 0; r < 4; ++r) sacc[g][r] = 0.f;

    const float scale = 0.17677669529663687f;  // 32^-0.5
    const float* xb_base = x + (size_t)b * CIN * NPOS;

    for (int tt = 0; tt < TA; ++tt) {
        int tile = bx * TA + tt;

        // ---- stage x tile: lane l owns position l; walks channel pairs.
        // Per-instr banks: 4*(l&7) + ((l>>4)+it)&3 -> 32 distinct x 2 lanes = 2-way (free).
        // Loads: per (it), 4 rows x 64B contiguous; 32 dwords in flight per wave.
        {
            const float* xc = xb_base + tile * 64 + l;
#pragma unroll
            for (int it = 0; it < 16; ++it) {
                int c = ((it >> 2) * 32) + w * 8 + ((((l >> 4) + it) & 3) * 2);
                float a0 = xc[(size_t)c * NPOS];
                float a1 = xc[(size_t)(c + 1) * NPOS];
                ushort2 u; u.x = f2b(a0); u.y = f2b(a1);
                *(ushort2*)(&xt[l][c]) = u;
            }
        }
        __syncthreads();

#pragma unroll
        for (int c4 = 0; c4 < 2; ++c4) {
            bf16x8 xb[2][4];
#pragma unroll
            for (int nt = 0; nt < 2; ++nt)
#pragma unroll
                for (int kk = 0; kk < 4; ++kk)
                    xb[nt][kk] = *(const bf16x8*)(&xt[c4 * 32 + nt * 16 + lr][kk * 32 + lq * 8]);

            f32x4 kacc[2][2], vacc[2][2], qacc[2][2];
#pragma unroll
            for (int g = 0; g < 2; ++g)
#pragma unroll
                for (int nt = 0; nt < 2; ++nt) {
                    kacc[g][nt] = (f32x4){0.f, 0.f, 0.f, 0.f};
                    vacc[g][nt] = (f32x4){0.f, 0.f, 0.f, 0.f};
                    qacc[g][nt] = (f32x4){0.f, 0.f, 0.f, 0.f};
                }
#pragma unroll
            for (int g = 0; g < 2; ++g)
#pragma unroll
                for (int nt = 0; nt < 2; ++nt)
#pragma unroll
                    for (int kk = 0; kk < 4; ++kk) {
                        kacc[g][nt] = __builtin_amdgcn_mfma_f32_16x16x32_bf16(ka[g][kk], xb[nt][kk], kacc[g][nt], 0, 0, 0);
                        vacc[g][nt] = __builtin_amdgcn_mfma_f32_16x16x32_bf16(va[g][kk], xb[nt][kk], vacc[g][nt], 0, 0, 0);
                        qacc[g][nt] = __builtin_amdgcn_mfma_f32_16x16x32_bf16(qa[g][kk], xb[nt][kk], qacc[g][nt], 0, 0, 0);
                    }

            // exp(k) + transpose k,v into per-wave LDS (wave-private -> no barrier needed)
#pragma unroll
            for (int g = 0; g < 2; ++g)
#pragma unroll
                for (int nt = 0; nt < 2; ++nt)
#pragma unroll
                    for (int r = 0; r < 4; ++r) {
                        float e_ = __expf(kacc[g][nt][r]);
                        sacc[g][r] += e_;
                        kb[w][g * 16 + lq * 4 + r][nt * 16 + lr] = f2b(e_);
                        vb[w][g * 16 + lq * 4 + r][nt * 16 + lr] = f2b(vacc[g][nt][r]);
                    }

            bf16x8 ak[2], av[2];
#pragma unroll
            for (int mt = 0; mt < 2; ++mt) ak[mt] = *(const bf16x8*)(&kb[w][mt * 16 + lr][lq * 8]);
#pragma unroll
            for (int nt = 0; nt < 2; ++nt) av[nt] = *(const bf16x8*)(&vb[w][nt * 16 + lr][lq * 8]);
#pragma unroll
            for (int mt = 0; mt < 2; ++mt)
#pragma unroll
                for (int nt = 0; nt < 2; ++nt)
                    cacc[mt][nt] = __builtin_amdgcn_mfma_f32_16x16x32_bf16(ak[mt], av[nt], cacc[mt][nt], 0, 0, 0);

            // q softmax over d (32 channels of head w) per position; store q~ straight to
            // global with the SAME swizzled byte layout the old LDS+copy produced.
#pragma unroll
            for (int nt = 0; nt < 2; ++nt) {
                float m = -1e30f;
#pragma unroll
                for (int g = 0; g < 2; ++g)
#pragma unroll
                    for (int r = 0; r < 4; ++r) m = fmaxf(m, qacc[g][nt][r]);
                m = fmaxf(m, __shfl_xor(m, 16));
                m = fmaxf(m, __shfl_xor(m, 32));
                float ee[2][4], s = 0.f;
#pragma unroll
                for (int g = 0; g < 2; ++g)
#pragma unroll
                    for (int r = 0; r < 4; ++r) { ee[g][r] = __expf(qacc[g][nt][r] - m); s += ee[g][r]; }
                s += __shfl_xor(s, 16);
                s += __shfl_xor(s, 32);
                float inv = scale / s;
                int pos = c4 * 32 + nt * 16 + lr;
                char* qrow = (char*)qt + (((size_t)b * 256 + tile) * 16384) + pos * 256;
#pragma unroll
                for (int g = 0; g < 2; ++g) {
                    ushort4 u;
                    u.x = f2b(ee[g][0] * inv); u.y = f2b(ee[g][1] * inv);
                    u.z = f2b(ee[g][2] * inv); u.w = f2b(ee[g][3] * inv);
                    int byteoff = (((w * 32 + g * 16 + lq * 4) * 2) ^ ((pos & 7) << 4));
                    *(ushort4*)(qrow + byteoff) = u;
                }
            }
        }
        __syncthreads();   // xt reads done before next tile's stage overwrites it
    }

    // non-atomic partial writes (this block is unique per (bx,b))
#pragma unroll
    for (int mt = 0; mt < 2; ++mt)
#pragma unroll
        for (int nt = 0; nt < 2; ++nt)
#pragma unroll
            for (int r = 0; r < 4; ++r)
                ctx_part[(((size_t)bx * 16 + b) * 4 + w) * 1024 +
                         (size_t)(mt * 16 + lq * 4 + r) * 32 + nt * 16 + lr] = cacc[mt][nt][r];

#pragma unroll
    for (int g = 0; g < 2; ++g)
#pragma unroll
        for (int r = 0; r < 4; ++r) {
            float s = sacc[g][r];
            s += __shfl_xor(s, 1); s += __shfl_xor(s, 2);
            s += __shfl_xor(s, 4); s += __shfl_xor(s, 8);
            if (lr == 0)
                kexp_part[((size_t)bx * 16 + b) * 128 + w * 32 + g * 16 + lq * 4 + r] = s;
        }
}

// ---------------- Kernel B2: reduce partials; Weff[b][c][h*32+d] = (1/kexp)*sum_e wo*ctx ----------------
__global__ __launch_bounds__(256) void k_weff2(const float* __restrict__ wo,
                                               const float* __restrict__ ctx_part,
                                               const float* __restrict__ kexp_part,
                                               ushort_t* __restrict__ weff) {
    int bh = blockIdx.x, b = bh >> 2, h = bh & 3;
    __shared__ float wos[128][32];
    __shared__ float cs[32][33];
    __shared__ float kinv[32];
    int t = threadIdx.x;

    // reduce ctx partials: thread t owns cells [4t, 4t+4)
    float4 a = {0.f, 0.f, 0.f, 0.f};
#pragma unroll 4
    for (int g = 0; g < GA; ++g) {
        float4 v = *(const float4*)&ctx_part[(((size_t)g * 16 + b) * 4 + h) * 1024 + t * 4];
        a.x += v.x; a.y += v.y; a.z += v.z; a.w += v.w;
    }
    {
        int d = t >> 3, e0 = (t & 7) * 4;
        cs[d][e0 + 0] = a.x; cs[d][e0 + 1] = a.y; cs[d][e0 + 2] = a.z; cs[d][e0 + 3] = a.w;
    }
    if (t < 32) {
        float s = 0.f;
#pragma unroll 4
        for (int g = 0; g < GA; ++g) s += kexp_part[((size_t)g * 16 + b) * 128 + h * 32 + t];
        kinv[t] = 1.0f / s;
    }
#pragma unroll
    for (int k = 0; k < 16; ++k) {
        int idx = k * 256 + t; int c = idx >> 5, e = idx & 31;
        wos[c][e] = wo[(size_t)c * HID + h * 32 + e];
    }
    __syncthreads();
#pragma unroll
    for (int k = 0; k < 16; ++k) {
        int idx = k * 256 + t; int c = idx >> 5, d = idx & 31;
        float s = 0.f;
#pragma unroll
        for (int e = 0; e < 32; ++e) s += wos[c][e] * cs[d][e];
        weff[((size_t)b * HID + c) * HID + h * 32 + d] = f2b(s * kinv[d]);
    }
}

// ---------------- Kernel C2: out = Weff @ q~ + bias -> LayerNorm (no x read, no q GEMM) ----------------
__global__ __launch_bounds__(256) void k_outf2(const ushort_t* __restrict__ qt,
                                               const ushort_t* __restrict__ weff,
                                               const float* __restrict__ bout,
                                               const float* __restrict__ lng,
                                               const float* __restrict__ lnb,
                                               float* __restrict__ out) {
    __shared__ __align__(16) ushort_t qs[64 * 128];   // swizzled q~ tile
    __shared__ float redS[4][64], redQ[4][64];
    int t = threadIdx.x, b = blockIdx.y, tile = blockIdx.x, p0 = tile * 64;
    int w = t >> 6, l = t & 63, lr = l & 15, lq = l >> 4;

    // stage q~ tile (16 KB, linear copy; layout already swizzled)
    {
        const uint4* s4 = (const uint4*)(qt + ((size_t)b * 256 + tile) * 8192);
        uint4* d4 = (uint4*)qs;
#pragma unroll
        for (int it = 0; it < 4; ++it) d4[it * 256 + t] = s4[it * 256 + t];
    }

    bf16x8 wa[2][4];
#pragma unroll
    for (int g = 0; g < 2; ++g)
#pragma unroll
        for (int kk = 0; kk < 4; ++kk)
            wa[g][kk] = *(const bf16x8*)(weff + ((size_t)b * HID + w * 32 + g * 16 + lr) * HID + kk * 32 + lq * 8);
    __syncthreads();

    f32x4 oacc[2][4];
#pragma unroll
    for (int g = 0; g < 2; ++g)
#pragma unroll
        for (int j = 0; j < 4; ++j) oacc[g][j] = (f32x4){0.f, 0.f, 0.f, 0.f};
#pragma unroll
    for (int j = 0; j < 4; ++j) {
        bf16x8 sb[4];
#pragma unroll
        for (int kk = 0; kk < 4; ++kk) {
            int pos = j * 16 + lr;
            int off = pos * 256 + ((kk * 64 + lq * 16) ^ ((pos & 7) << 4));
            sb[kk] = *(const bf16x8*)((const char*)qs + off);
        }
#pragma unroll
        for (int g = 0; g < 2; ++g)
#pragma unroll
            for (int kk = 0; kk < 4; ++kk)
                oacc[g][j] = __builtin_amdgcn_mfma_f32_16x16x32_bf16(wa[g][kk], sb[kk], oacc[g][j], 0, 0, 0);
    }

    // bias + LayerNorm over 128 channels per position
    float vals[2][4][4];
    float colS[4] = {0.f, 0.f, 0.f, 0.f}, colQ[4] = {0.f, 0.f, 0.f, 0.f};
#pragma unroll
    for (int g = 0; g < 2; ++g)
#pragma unroll
        for (int r = 0; r < 4; ++r) {
            int c = w * 32 + g * 16 + lq * 4 + r;
            float bias = bout[c];
#pragma unroll
            for (int j = 0; j < 4; ++j) {
                float v = oacc[g][j][r] + bias;
                vals[g][j][r] = v;
                colS[j] += v;
                colQ[j] += v * v;
            }
        }
#pragma unroll
    for (int j = 0; j < 4; ++j) {
        colS[j] += __shfl_xor(colS[j], 16); colQ[j] += __shfl_xor(colQ[j], 16);
        colS[j] += __shfl_xor(colS[j], 32); colQ[j] += __shfl_xor(colQ[j], 32);
        if (lq == 0) { redS[w][j * 16 + lr] = colS[j]; redQ[w][j * 16 + lr] = colQ[j]; }
    }
    __syncthreads();

    float mean[4], rstd[4];
#pragma unroll
    for (int j = 0; j < 4; ++j) {
        int col = j * 16 + lr;
        float S = redS[0][col] + redS[1][col] + redS[2][col] + redS[3][col];
        float Q = redQ[0][col] + redQ[1][col] + redQ[2][col] + redQ[3][col];
        float mu = S * (1.f / 128.f);
        float var = Q * (1.f / 128.f) - mu * mu;
        mean[j] = mu;
        rstd[j] = rsqrtf(var + 1e-5f);
    }

#pragma unroll
    for (int g = 0; g < 2; ++g)
#pragma unroll
        for (int r = 0; r < 4; ++r) {
            int c = w * 32 + g * 16 + lq * 4 + r;
            float gg = lng[c], lb = lnb[c];
#pragma unroll
            for (int j = 0; j < 4; ++j)
                out[((size_t)b * HID + c) * NPOS + p0 + j * 16 + lr] =
                    (vals[g][j][r] - mean[j]) * rstd[j] * gg + lb;
        }
}

// =================================================================================
// FALLBACK PATH (verified previous kernel) — used if workspace is too small
// =================================================================================

__global__ __launch_bounds__(256) void k_ctxsum(const float* __restrict__ x,
                                                const ushort_t* __restrict__ wq,
                                                float* __restrict__ kexp,
                                                float* __restrict__ ctx) {
    __shared__ ushort_t xt[64][136];
    __shared__ ushort_t kb[4][32][40];
    __shared__ ushort_t vb[4][32][40];
    int t = threadIdx.x, b = blockIdx.y, p0 = blockIdx.x * 64;
    stage_x64(x + (size_t)b * CIN * NPOS + p0, t, xt);

    int w = t >> 6, l = t & 63, lr = l & 15, lq = l >> 4;

    bf16x8 ka[2][4], va[2][4];
#pragma unroll
    for (int g = 0; g < 2; ++g)
#pragma unroll
        for (int kk = 0; kk < 4; ++kk) {
            ka[g][kk] = *(const bf16x8*)(wq + (size_t)(128 + w * 32 + g * 16 + lr) * CIN + kk * 32 + lq * 8);
            va[g][kk] = *(const bf16x8*)(wq + (size_t)(256 + w * 32 + g * 16 + lr) * CIN + kk * 32 + lq * 8);
        }
    __syncthreads();

    f32x4 cacc[2][2];
#pragma unroll
    for (int mt = 0; mt < 2; ++mt)
#pragma unroll
        for (int nt = 0; nt < 2; ++nt) cacc[mt][nt] = (f32x4){0.f, 0.f, 0.f, 0.f};
    float sacc[2][4];
#pragma unroll
    for (int g = 0; g < 2; ++g)
#pragma unroll
        for (int r = 0; r < 4; ++r) sacc[g][r] = 0.f;

#pragma unroll
    for (int c4 = 0; c4 < 2; ++c4) {
        bf16x8 xb[2][4];
#pragma unroll
        for (int nt = 0; nt < 2; ++nt)
#pragma unroll
            for (int kk = 0; kk < 4; ++kk)
                xb[nt][kk] = *(const bf16x8*)(&xt[c4 * 32 + nt * 16 + lr][kk * 32 + lq * 8]);

        f32x4 kacc[2][2], vacc[2][2];
#pragma unroll
        for (int g = 0; g < 2; ++g)
#pragma unroll
            for (int nt = 0; nt < 2; ++nt) {
                kacc[g][nt] = (f32x4){0.f, 0.f, 0.f, 0.f};
                vacc[g][nt] = (f32x4){0.f, 0.f, 0.f, 0.f};
            }
#pragma unroll
        for (int g = 0; g < 2; ++g)
#pragma unroll
            for (int nt = 0; nt < 2; ++nt)
#pragma unroll
                for (int kk = 0; kk < 4; ++kk) {
                    kacc[g][nt] = __builtin_amdgcn_mfma_f32_16x16x32_bf16(ka[g][kk], xb[nt][kk], kacc[g][nt], 0, 0, 0);
                    vacc[g][nt] = __builtin_amdgcn_mfma_f32_16x16x32_bf16(va[g][kk], xb[nt][kk], vacc[g][nt], 0, 0, 0);
                }

#pragma unroll
        for (int g = 0; g < 2; ++g)
#pragma unroll
            for (int nt = 0; nt < 2; ++nt)
#pragma unroll
                for (int r = 0; r < 4; ++r) {
                    float e = __expf(kacc[g][nt][r]);
                    sacc[g][r] += e;
                    kb[w][g * 16 + lq * 4 + r][nt * 16 + lr] = f2b(e);
                    vb[w][g * 16 + lq * 4 + r][nt * 16 + lr] = f2b(vacc[g][nt][r]);
                }
        __syncthreads();

        bf16x8 ak[2], av[2];
#pragma unroll
        for (int mt = 0; mt < 2; ++mt) ak[mt] = *(const bf16x8*)(&kb[w][mt * 16 + lr][lq * 8]);
#pragma unroll
        for (int nt = 0; nt < 2; ++nt) av[nt] = *(const bf16x8*)(&vb[w][nt * 16 + lr][lq * 8]);
#pragma unroll
        for (int mt = 0; mt < 2; ++mt)
#pragma unroll
            for (int nt = 0; nt < 2; ++nt)
                cacc[mt][nt] = __builtin_amdgcn_mfma_f32_16x16x32_bf16(ak[mt], av[nt], cacc[mt][nt], 0, 0, 0);
        __syncthreads();
    }

#pragma unroll
    for (int mt = 0; mt < 2; ++mt)
#pragma unroll
        for (int nt = 0; nt < 2; ++nt)
#pragma unroll
            for (int r = 0; r < 4; ++r)
                atomicAdd(&ctx[((size_t)(b * 4 + w) * 32 + mt * 16 + lq * 4 + r) * 32 + nt * 16 + lr],
                          cacc[mt][nt][r]);

#pragma unroll
    for (int g = 0; g < 2; ++g)
#pragma unroll
        for (int r = 0; r < 4; ++r) {
            float s = sacc[g][r];
            s += __shfl_xor(s, 1); s += __shfl_xor(s, 2);
            s += __shfl_xor(s, 4); s += __shfl_xor(s, 8);
            if (lr == 0)
                atomicAdd(&kexp[(b * 4 + w) * 32 + g * 16 + lq * 4 + r], s);
        }
}

__global__ __launch_bounds__(256) void k_weff(const float* __restrict__ wo,
                                              const float* __restrict__ ctx,
                                              const float* __restrict__ kexp,
                                              ushort_t* __restrict__ weff) {
    int bh = blockIdx.x, b = bh >> 2, h = bh & 3;
    __shared__ float wos[128][32];
    __shared__ float cs[32][33];
    int t = threadIdx.x;
#pragma unroll
    for (int k = 0; k < 16; ++k) {
        int idx = k * 256 + t; int c = idx >> 5, e = idx & 31;
        wos[c][e] = wo[(size_t)c * HID + h * 32 + e];
    }
#pragma unroll
    for (int k = 0; k < 4; ++k) {
        int idx = k * 256 + t; int d = idx >> 5, e = idx & 31;
        cs[d][e] = ctx[((size_t)bh * 32 + d) * 32 + e];
    }
    __syncthreads();
#pragma unroll
    for (int k = 0; k < 16; ++k) {
        int idx = k * 256 + t; int c = idx >> 5, d = idx & 31;
        float s = 0.f;
#pragma unroll
        for (int e = 0; e < 32; ++e) s += wos[c][e] * cs[d][e];
        float kin = 1.0f / kexp[bh * 32 + d];
        weff[((size_t)b * HID + c) * HID + h * 32 + d] = f2b(s * kin);
    }
}

__global__ __launch_bounds__(256) void k_outf(const float* __restrict__ x,
                                              const ushort_t* __restrict__ wq,
                                              const ushort_t* __restrict__ weff,
                                              const float* __restrict__ bout,
                                              const float* __restrict__ lng,
                                              const float* __restrict__ lnb,
                                              float* __restrict__ out) {
    __shared__ ushort_t buf[64][136];
    __shared__ float redS[4][64], redQ[4][64];
    int t = threadIdx.x, b = blockIdx.y, p0 = blockIdx.x * 64;
    stage_x64(x + (size_t)b * CIN * NPOS + p0, t, buf);

    int w = t >> 6, l = t & 63, lr = l & 15, lq = l >> 4;

    bf16x8 qa[2][4];
#pragma unroll
    for (int g = 0; g < 2; ++g)
#pragma unroll
        for (int kk = 0; kk < 4; ++kk)
            qa[g][kk] = *(const bf16x8*)(wq + (size_t)(w * 32 + g * 16 + lr) * CIN + kk * 32 + lq * 8);
    __syncthreads();

    f32x4 qacc[2][4];
#pragma unroll
    for (int g = 0; g < 2; ++g)
#pragma unroll
        for (int j = 0; j < 4; ++j) qacc[g][j] = (f32x4){0.f, 0.f, 0.f, 0.f};
#pragma unroll
    for (int j = 0; j < 4; ++j) {
        bf16x8 xb[4];
#pragma unroll
        for (int kk = 0; kk < 4; ++kk)
            xb[kk] = *(const bf16x8*)(&buf[j * 16 + lr][kk * 32 + lq * 8]);
#pragma unroll
        for (int g = 0; g < 2; ++g)
#pragma unroll
            for (int kk = 0; kk < 4; ++kk)
                qacc[g][j] = __builtin_amdgcn_mfma_f32_16x16x32_bf16(qa[g][kk], xb[kk], qacc[g][j], 0, 0, 0);
    }
    __syncthreads();

    const float scale = 0.17677669529663687f;
#pragma unroll
    for (int j = 0; j < 4; ++j) {
        float m = -1e30f;
#pragma unroll
        for (int g = 0; g < 2; ++g)
#pragma unroll
            for (int r = 0; r < 4; ++r) m = fmaxf(m, qacc[g][j][r]);
        m = fmaxf(m, __shfl_xor(m, 16));
        m = fmaxf(m, __shfl_xor(m, 32));
        float e[2][4], s = 0.f;
#pragma unroll
        for (int g = 0; g < 2; ++g)
#pragma unroll
            for (int r = 0; r < 4; ++r) { e[g][r] = __expf(qacc[g][j][r] - m); s += e[g][r]; }
        s += __shfl_xor(s, 16);
        s += __shfl_xor(s, 32);
        float inv = scale / s;
#pragma unroll
        for (int g = 0; g < 2; ++g) {
            ushort4 u;
            u.x = f2b(e[g][0] * inv); u.y = f2b(e[g][1] * inv);
            u.z = f2b(e[g][2] * inv); u.w = f2b(e[g][3] * inv);
            *(ushort4*)(&buf[j * 16 + lr][w * 32 + g * 16 + lq * 4]) = u;
        }
    }
    __syncthreads();

    bf16x8 wa[2][4];
#pragma unroll
    for (int g = 0; g < 2; ++g)
#pragma unroll
        for (int kk = 0; kk < 4; ++kk)
            wa[g][kk] = *(const bf16x8*)(weff + ((size_t)b * HID + w * 32 + g * 16 + lr) * HID + kk * 32 + lq * 8);
    f32x4 oacc[2][4];
#pragma unroll
    for (int g = 0; g < 2; ++g)
#pragma unroll
        for (int j = 0; j < 4; ++j) oacc[g][j] = (f32x4){0.f, 0.f, 0.f, 0.f};
#pragma unroll
    for (int j = 0; j < 4; ++j) {
        bf16x8 sb[4];
#pragma unroll
        for (int kk = 0; kk < 4; ++kk)
            sb[kk] = *(const bf16x8*)(&buf[j * 16 + lr][kk * 32 + lq * 8]);
#pragma unroll
        for (int g = 0; g < 2; ++g)
#pragma unroll
            for (int kk = 0; kk < 4; ++kk)
                oacc[g][j] = __builtin_amdgcn_mfma_f32_16x16x32_bf16(wa[g][kk], sb[kk], oacc[g][j], 0, 0, 0);
    }

    float vals[2][4][4];
    float colS[4] = {0.f, 0.f, 0.f, 0.f}, colQ[4] = {0.f, 0.f, 0.f, 0.f};
#pragma unroll
    for (int g = 0; g < 2; ++g)
#pragma unroll
        for (int r = 0; r < 4; ++r) {
            int c = w * 32 + g * 16 + lq * 4 + r;
            float bias = bout[c];
#pragma unroll
            for (int j = 0; j < 4; ++j) {
                float v = oacc[g][j][r] + bias;
                vals[g][j][r] = v;
                colS[j] += v;
                colQ[j] += v * v;
            }
        }
#pragma unroll
    for (int j = 0; j < 4; ++j) {
        colS[j] += __shfl_xor(colS[j], 16); colQ[j] += __shfl_xor(colQ[j], 16);
        colS[j] += __shfl_xor(colS[j], 32); colQ[j] += __shfl_xor(colQ[j], 32);
        if (lq == 0) { redS[w][j * 16 + lr] = colS[j]; redQ[w][j * 16 + lr] = colQ[j]; }
    }
    __syncthreads();

    float mean[4], rstd[4];
#pragma unroll
    for (int j = 0; j < 4; ++j) {
        int col = j * 16 + lr;
        float S = redS[0][col] + redS[1][col] + redS[2][col] + redS[3][col];
        float Q = redQ[0][col] + redQ[1][col] + redQ[2][col] + redQ[3][col];
        float mu = S * (1.f / 128.f);
        float var = Q * (1.f / 128.f) - mu * mu;
        mean[j] = mu;
        rstd[j] = rsqrtf(var + 1e-5f);
    }

#pragma unroll
    for (int g = 0; g < 2; ++g)
#pragma unroll
        for (int r = 0; r < 4; ++r) {
            int c = w * 32 + g * 16 + lq * 4 + r;
            float gg = lng[c], lb = lnb[c];
#pragma unroll
            for (int j = 0; j < 4; ++j)
                out[((size_t)b * HID + c) * NPOS + p0 + j * 16 + lr] =
                    (vals[g][j][r] - mean[j]) * rstd[j] * gg + lb;
        }
}

extern "C" void kernel_launch(void* const* d_in, const int* in_sizes, int n_in,
                              void* d_out, int out_size, void* d_ws, size_t ws_size,
                              hipStream_t stream) {
    const float* x    = (const float*)d_in[0];
    const float* wqkv = (const float*)d_in[1];
    const float* wout = (const float*)d_in[2];
    const float* bout = (const float*)d_in[3];
    const float* lng  = (const float*)d_in[4];
    const float* lnb  = (const float*)d_in[5];
    float* out = (float*)d_out;

    char* ws = (char*)d_ws;

    // new-path workspace layout
    const size_t off_kexp = 0;                     // GA*16*128 f32      = 512 KB
    const size_t off_ctxp = 524288;                // GA*16*4096 f32     = 16 MB
    const size_t off_wqbf = 17301504;              // 49152 bf16         = 96 KB
    const size_t off_weff = 17399808;              // 16*128*128 bf16    = 512 KB
    const size_t off_qt   = 17924096;              // 16*16384*128 bf16  = 64 MB
    const size_t NEED     = 85032960;

    if (ws_size >= NEED) {
        float*    kexp_part = (float*)(ws + off_kexp);
        float*    ctx_part  = (float*)(ws + off_ctxp);
        ushort_t* wq_bf     = (ushort_t*)(ws + off_wqbf);
        ushort_t* weff      = (ushort_t*)(ws + off_weff);
        ushort_t* qt        = (ushort_t*)(ws + off_qt);

        k_cvt<<<dim3(192), dim3(256), 0, stream>>>(wqkv, wq_bf);
        k_ctxsum2<<<dim3(GA, 16), dim3(256), 0, stream>>>(x, wq_bf, kexp_part, ctx_part, qt);
        k_weff2<<<dim3(64), dim3(256), 0, stream>>>(wout, ctx_part, kexp_part, weff);
        k_outf2<<<dim3(NPOS / 64, 16), dim3(256), 0, stream>>>(qt, weff, bout, lng, lnb, out);
    } else {
        // fallback: previous verified path
        float*    kexp  = (float*)ws;
        float*    ctx   = (float*)(ws + 8192);
        ushort_t* wq_bf = (ushort_t*)(ws + 270336);
        ushort_t* weff  = (ushort_t*)(ws + 368640);

        hipMemsetAsync(ws, 0, 270336, stream);

        k_cvt<<<dim3(192), dim3(256), 0, stream>>>(wqkv, wq_bf);
        k_ctxsum<<<dim3(NPOS / 64, 16), dim3(256), 0, stream>>>(x, wq_bf, kexp, ctx);
        k_weff<<<dim3(64), dim3(256), 0, stream>>>(wout, ctx, kexp, weff);
        k_outf<<<dim3(NPOS / 64, 16), dim3(256), 0, stream>>>(x, wq_bf, weff, bout, lng, lnb, out);
    }
}

// Round 3
// 334.927 us; speedup vs baseline: 1.3432x; 1.3432x over previous
//
#include <hip/hip_runtime.h>

typedef unsigned short ushort_t;
typedef __attribute__((ext_vector_type(8))) short bf16x8;
typedef __attribute__((ext_vector_type(4))) float f32x4;

#define NPOS 16384   // H*W
#define CIN 128
#define O3  384
#define HID 128
#define GA  64       // kernel A grid.x
#define TA  4        // position tiles (of 64) per A block; GA*TA = 256

__device__ inline float b2f(ushort_t u) {
    union { unsigned int i; float f; } z; z.i = ((unsigned int)u) << 16; return z.f;
}
__device__ inline ushort_t f2b(float f) {
    union { float f; unsigned int u; } x; x.f = f;
    unsigned int lsb = (x.u >> 16) & 1u;
    unsigned int r = x.u + 0x7fffu + lsb;
    return (ushort_t)(r >> 16);
}

// ---------------- Kernel 0: one-time fp32 -> bf16 conversion of w_qkv ----------------
__global__ __launch_bounds__(256) void k_cvt(const float* __restrict__ wq,
                                             ushort_t* __restrict__ wq_bf) {
    int i = blockIdx.x * 256 + threadIdx.x;   // 0 .. 49151
    wq_bf[i] = f2b(wq[i]);
}

// Stage a (128 ch x 64 pos) fp32 tile -> bf16 LDS [pos][ch(136)]
// (float4 loads, 4x256B contiguous per instruction; LDS writes 16-way conflicted but
//  measured cost is only ~15us across the whole A kernel -- accepted, R1-verified.)
__device__ inline void stage_x64(const float* __restrict__ x, int t, ushort_t (*xt)[136]) {
    int q4 = t & 15;          // position quad 0..15
    int ch0 = t >> 4;         // 0..15
    const float* xp = x + q4 * 4;
#pragma unroll
    for (int it = 0; it < 8; ++it) {
        int c = it * 16 + ch0;
        float4 v = *(const float4*)(xp + (size_t)c * NPOS);
        xt[q4 * 4 + 0][c] = f2b(v.x);
        xt[q4 * 4 + 1][c] = f2b(v.y);
        xt[q4 * 4 + 2][c] = f2b(v.z);
        xt[q4 * 4 + 3][c] = f2b(v.w);
    }
}

// =================================================================================
// NEW PATH: atomic-free partials + q~ produced in pass A (single fp32 read of x)
// =================================================================================

// ---------------- Kernel A2 (R1-verified, 134us): q/k/v GEMM; q softmax -> q~ (bf16,
//   swizzled tile via LDS bounce + coalesced copy); exp(k)&v -> ctx/kexp reg accum ----
__global__ __launch_bounds__(256) void k_ctxsum2(const float* __restrict__ x,
                                                 const ushort_t* __restrict__ wq,
                                                 float* __restrict__ kexp_part,
                                                 float* __restrict__ ctx_part,
                                                 ushort_t* __restrict__ qt) {
    __shared__ __align__(16) ushort_t xt[64][136];   // x tile; reused as q~ tile buffer
    __shared__ ushort_t kb[4][32][40];   // per-wave exp(k) transpose: [d][pos]
    __shared__ ushort_t vb[4][32][40];   // per-wave v transpose
    int t = threadIdx.x, b = blockIdx.y, bx = blockIdx.x;
    int w = t >> 6, l = t & 63, lr = l & 15, lq = l >> 4;

    // hoisted weight fragments (reused across TA tiles x 2 chunks)
    bf16x8 qa[2][4], ka[2][4], va[2][4];
#pragma unroll
    for (int g = 0; g < 2; ++g)
#pragma unroll
        for (int kk = 0; kk < 4; ++kk) {
            qa[g][kk] = *(const bf16x8*)(wq + (size_t)(      w * 32 + g * 16 + lr) * CIN + kk * 32 + lq * 8);
            ka[g][kk] = *(const bf16x8*)(wq + (size_t)(128 + w * 32 + g * 16 + lr) * CIN + kk * 32 + lq * 8);
            va[g][kk] = *(const bf16x8*)(wq + (size_t)(256 + w * 32 + g * 16 + lr) * CIN + kk * 32 + lq * 8);
        }

    f32x4 cacc[2][2];
#pragma unroll
    for (int mt = 0; mt < 2; ++mt)
#pragma unroll
        for (int nt = 0; nt < 2; ++nt) cacc[mt][nt] = (f32x4){0.f, 0.f, 0.f, 0.f};
    float sacc[2][4];
#pragma unroll
    for (int g = 0; g < 2; ++g)
#pragma unroll
        for (int r = 0; r < 4; ++r) sacc[g][r] = 0.f;

    const float scale = 0.17677669529663687f;  // 32^-0.5

    for (int tt = 0; tt < TA; ++tt) {
        int tile = bx * TA + tt;
        stage_x64(x + (size_t)b * CIN * NPOS + tile * 64, t, xt);
        __syncthreads();

        ushort4 qpk[2][2][2];   // [c4][nt][g] packed q~ (4 consecutive channels)

#pragma unroll
        for (int c4 = 0; c4 < 2; ++c4) {
            bf16x8 xb[2][4];
#pragma unroll
            for (int nt = 0; nt < 2; ++nt)
#pragma unroll
                for (int kk = 0; kk < 4; ++kk)
                    xb[nt][kk] = *(const bf16x8*)(&xt[c4 * 32 + nt * 16 + lr][kk * 32 + lq * 8]);

            f32x4 kacc[2][2], vacc[2][2], qacc[2][2];
#pragma unroll
            for (int g = 0; g < 2; ++g)
#pragma unroll
                for (int nt = 0; nt < 2; ++nt) {
                    kacc[g][nt] = (f32x4){0.f, 0.f, 0.f, 0.f};
                    vacc[g][nt] = (f32x4){0.f, 0.f, 0.f, 0.f};
                    qacc[g][nt] = (f32x4){0.f, 0.f, 0.f, 0.f};
                }
#pragma unroll
            for (int g = 0; g < 2; ++g)
#pragma unroll
                for (int nt = 0; nt < 2; ++nt)
#pragma unroll
                    for (int kk = 0; kk < 4; ++kk) {
                        kacc[g][nt] = __builtin_amdgcn_mfma_f32_16x16x32_bf16(ka[g][kk], xb[nt][kk], kacc[g][nt], 0, 0, 0);
                        vacc[g][nt] = __builtin_amdgcn_mfma_f32_16x16x32_bf16(va[g][kk], xb[nt][kk], vacc[g][nt], 0, 0, 0);
                        qacc[g][nt] = __builtin_amdgcn_mfma_f32_16x16x32_bf16(qa[g][kk], xb[nt][kk], qacc[g][nt], 0, 0, 0);
                    }

            // exp(k) + transpose k,v into per-wave LDS (wave-private -> no barrier needed)
#pragma unroll
            for (int g = 0; g < 2; ++g)
#pragma unroll
                for (int nt = 0; nt < 2; ++nt)
#pragma unroll
                    for (int r = 0; r < 4; ++r) {
                        float e_ = __expf(kacc[g][nt][r]);
                        sacc[g][r] += e_;
                        kb[w][g * 16 + lq * 4 + r][nt * 16 + lr] = f2b(e_);
                        vb[w][g * 16 + lq * 4 + r][nt * 16 + lr] = f2b(vacc[g][nt][r]);
                    }

            bf16x8 ak[2], av[2];
#pragma unroll
            for (int mt = 0; mt < 2; ++mt) ak[mt] = *(const bf16x8*)(&kb[w][mt * 16 + lr][lq * 8]);
#pragma unroll
            for (int nt = 0; nt < 2; ++nt) av[nt] = *(const bf16x8*)(&vb[w][nt * 16 + lr][lq * 8]);
#pragma unroll
            for (int mt = 0; mt < 2; ++mt)
#pragma unroll
                for (int nt = 0; nt < 2; ++nt)
                    cacc[mt][nt] = __builtin_amdgcn_mfma_f32_16x16x32_bf16(ak[mt], av[nt], cacc[mt][nt], 0, 0, 0);

            // q softmax over d (32 channels of head w) per position; pack to bf16 regs
#pragma unroll
            for (int nt = 0; nt < 2; ++nt) {
                float m = -1e30f;
#pragma unroll
                for (int g = 0; g < 2; ++g)
#pragma unroll
                    for (int r = 0; r < 4; ++r) m = fmaxf(m, qacc[g][nt][r]);
                m = fmaxf(m, __shfl_xor(m, 16));
                m = fmaxf(m, __shfl_xor(m, 32));
                float ee[2][4], s = 0.f;
#pragma unroll
                for (int g = 0; g < 2; ++g)
#pragma unroll
                    for (int r = 0; r < 4; ++r) { ee[g][r] = __expf(qacc[g][nt][r] - m); s += ee[g][r]; }
                s += __shfl_xor(s, 16);
                s += __shfl_xor(s, 32);
                float inv = scale / s;
#pragma unroll
                for (int g = 0; g < 2; ++g) {
                    ushort4 u;
                    u.x = f2b(ee[g][0] * inv); u.y = f2b(ee[g][1] * inv);
                    u.z = f2b(ee[g][2] * inv); u.w = f2b(ee[g][3] * inv);
                    qpk[c4][nt][g] = u;
                }
            }
        }

        __syncthreads();   // all waves done reading xt -> safe to overwrite with q~

        // write q~ into LDS [64 pos][128 ch], XOR-swizzled (byte ^= (pos&7)<<4)
        {
            ushort_t* qlds = (ushort_t*)&xt[0][0];
#pragma unroll
            for (int c4 = 0; c4 < 2; ++c4)
#pragma unroll
                for (int nt = 0; nt < 2; ++nt)
#pragma unroll
                    for (int g = 0; g < 2; ++g) {
                        int pos = c4 * 32 + nt * 16 + lr;
                        int byteoff = pos * 256 + (((w * 32 + g * 16 + lq * 4) * 2) ^ ((pos & 7) << 4));
                        *(ushort4*)((char*)qlds + byteoff) = qpk[c4][nt][g];
                    }
        }
        __syncthreads();

        // linear copy 16 KB q~ tile -> global (swizzle already applied in layout)
        {
            const uint4* s4 = (const uint4*)&xt[0][0];
            uint4* d4 = (uint4*)(qt + ((size_t)b * 256 + tile) * 8192);
#pragma unroll
            for (int it = 0; it < 4; ++it) d4[it * 256 + t] = s4[it * 256 + t];
        }
        __syncthreads();   // copy reads done before next tile's stage overwrites xt
    }

    // non-atomic partial writes (this block is unique per (bx,b))
#pragma unroll
    for (int mt = 0; mt < 2; ++mt)
#pragma unroll
        for (int nt = 0; nt < 2; ++nt)
#pragma unroll
            for (int r = 0; r < 4; ++r)
                ctx_part[(((size_t)bx * 16 + b) * 4 + w) * 1024 +
                         (size_t)(mt * 16 + lq * 4 + r) * 32 + nt * 16 + lr] = cacc[mt][nt][r];

#pragma unroll
    for (int g = 0; g < 2; ++g)
#pragma unroll
        for (int r = 0; r < 4; ++r) {
            float s = sacc[g][r];
            s += __shfl_xor(s, 1); s += __shfl_xor(s, 2);
            s += __shfl_xor(s, 4); s += __shfl_xor(s, 8);
            if (lr == 0)
                kexp_part[((size_t)bx * 16 + b) * 128 + w * 32 + g * 16 + lq * 4 + r] = s;
        }
}

// ---------------- Kernel B2: reduce partials; Weff[b][c][h*32+d] = (1/kexp)*sum_e wo*ctx ----------------
__global__ __launch_bounds__(256) void k_weff2(const float* __restrict__ wo,
                                               const float* __restrict__ ctx_part,
                                               const float* __restrict__ kexp_part,
                                               ushort_t* __restrict__ weff) {
    int bh = blockIdx.x, b = bh >> 2, h = bh & 3;
    __shared__ float wos[128][32];
    __shared__ float cs[32][33];
    __shared__ float kinv[32];
    int t = threadIdx.x;

    // reduce ctx partials: thread t owns cells [4t, 4t+4)  (full unroll -> 64 loads in flight)
    float4 a = {0.f, 0.f, 0.f, 0.f};
#pragma unroll 16
    for (int g = 0; g < GA; ++g) {
        float4 v = *(const float4*)&ctx_part[(((size_t)g * 16 + b) * 4 + h) * 1024 + t * 4];
        a.x += v.x; a.y += v.y; a.z += v.z; a.w += v.w;
    }
    {
        int d = t >> 3, e0 = (t & 7) * 4;
        cs[d][e0 + 0] = a.x; cs[d][e0 + 1] = a.y; cs[d][e0 + 2] = a.z; cs[d][e0 + 3] = a.w;
    }
    if (t < 32) {
        float s = 0.f;
#pragma unroll 16
        for (int g = 0; g < GA; ++g) s += kexp_part[((size_t)g * 16 + b) * 128 + h * 32 + t];
        kinv[t] = 1.0f / s;
    }
#pragma unroll
    for (int k = 0; k < 16; ++k) {
        int idx = k * 256 + t; int c = idx >> 5, e = idx & 31;
        wos[c][e] = wo[(size_t)c * HID + h * 32 + e];
    }
    __syncthreads();
#pragma unroll
    for (int k = 0; k < 16; ++k) {
        int idx = k * 256 + t; int c = idx >> 5, d = idx & 31;
        float s = 0.f;
#pragma unroll
        for (int e = 0; e < 32; ++e) s += wos[c][e] * cs[d][e];
        weff[((size_t)b * HID + c) * HID + h * 32 + d] = f2b(s * kinv[d]);
    }
}

// ---------------- Kernel C2: out = Weff @ q~ + bias -> LayerNorm ----------------
// q~ fragments are read DIRECTLY from global (no LDS staging, no barrier):
// all 4 waves share the same B-fragments; per load instr the 4 lq-lanes of each
// pos-row cover one aligned 64B segment (XOR bits 4-6 permute aligned 16B/64B
// blocks) -> 16x64B transactions, full efficiency, 16 loads in flight per thread.
__global__ __launch_bounds__(256) void k_outf2(const ushort_t* __restrict__ qt,
                                               const ushort_t* __restrict__ weff,
                                               const float* __restrict__ bout,
                                               const float* __restrict__ lng,
                                               const float* __restrict__ lnb,
                                               float* __restrict__ out) {
    __shared__ float redS[4][64], redQ[4][64];
    int t = threadIdx.x, b = blockIdx.y, tile = blockIdx.x, p0 = tile * 64;
    int w = t >> 6, l = t & 63, lr = l & 15, lq = l >> 4;

    const char* qbase = (const char*)(qt + ((size_t)b * 256 + tile) * 8192);

    bf16x8 wa[2][4];
#pragma unroll
    for (int g = 0; g < 2; ++g)
#pragma unroll
        for (int kk = 0; kk < 4; ++kk)
            wa[g][kk] = *(const bf16x8*)(weff + ((size_t)b * HID + w * 32 + g * 16 + lr) * HID + kk * 32 + lq * 8);

    f32x4 oacc[2][4];
#pragma unroll
    for (int g = 0; g < 2; ++g)
#pragma unroll
        for (int j = 0; j < 4; ++j) oacc[g][j] = (f32x4){0.f, 0.f, 0.f, 0.f};
#pragma unroll
    for (int j = 0; j < 4; ++j) {
        bf16x8 sb[4];
#pragma unroll
        for (int kk = 0; kk < 4; ++kk) {
            int pos = j * 16 + lr;
            sb[kk] = *(const bf16x8*)(qbase + pos * 256 + ((kk * 64 + lq * 16) ^ ((pos & 7) << 4)));
        }
#pragma unroll
        for (int g = 0; g < 2; ++g)
#pragma unroll
            for (int kk = 0; kk < 4; ++kk)
                oacc[g][j] = __builtin_amdgcn_mfma_f32_16x16x32_bf16(wa[g][kk], sb[kk], oacc[g][j], 0, 0, 0);
    }

    // bias + LayerNorm over 128 channels per position (no vals[] -- recompute at store)
    float bias_[2][4];
    float colS[4] = {0.f, 0.f, 0.f, 0.f}, colQ[4] = {0.f, 0.f, 0.f, 0.f};
#pragma unroll
    for (int g = 0; g < 2; ++g)
#pragma unroll
        for (int r = 0; r < 4; ++r) {
            int c = w * 32 + g * 16 + lq * 4 + r;
            bias_[g][r] = bout[c];
#pragma unroll
            for (int j = 0; j < 4; ++j) {
                float v = oacc[g][j][r] + bias_[g][r];
                colS[j] += v;
                colQ[j] += v * v;
            }
        }
#pragma unroll
    for (int j = 0; j < 4; ++j) {
        colS[j] += __shfl_xor(colS[j], 16); colQ[j] += __shfl_xor(colQ[j], 16);
        colS[j] += __shfl_xor(colS[j], 32); colQ[j] += __shfl_xor(colQ[j], 32);
        if (lq == 0) { redS[w][j * 16 + lr] = colS[j]; redQ[w][j * 16 + lr] = colQ[j]; }
    }
    __syncthreads();

    float mean[4], rstd[4];
#pragma unroll
    for (int j = 0; j < 4; ++j) {
        int col = j * 16 + lr;
        float S = redS[0][col] + redS[1][col] + redS[2][col] + redS[3][col];
        float Q = redQ[0][col] + redQ[1][col] + redQ[2][col] + redQ[3][col];
        float mu = S * (1.f / 128.f);
        float var = Q * (1.f / 128.f) - mu * mu;
        mean[j] = mu;
        rstd[j] = rsqrtf(var + 1e-5f);
    }

#pragma unroll
    for (int g = 0; g < 2; ++g)
#pragma unroll
        for (int r = 0; r < 4; ++r) {
            int c = w * 32 + g * 16 + lq * 4 + r;
            float gg = lng[c], lb = lnb[c];
#pragma unroll
            for (int j = 0; j < 4; ++j) {
                float v = oacc[g][j][r] + bias_[g][r];
                out[((size_t)b * HID + c) * NPOS + p0 + j * 16 + lr] =
                    (v - mean[j]) * rstd[j] * gg + lb;
            }
        }
}

// =================================================================================
// FALLBACK PATH (verified previous kernel) — used if workspace is too small
// =================================================================================

__global__ __launch_bounds__(256) void k_ctxsum(const float* __restrict__ x,
                                                const ushort_t* __restrict__ wq,
                                                float* __restrict__ kexp,
                                                float* __restrict__ ctx) {
    __shared__ ushort_t xt[64][136];
    __shared__ ushort_t kb[4][32][40];
    __shared__ ushort_t vb[4][32][40];
    int t = threadIdx.x, b = blockIdx.y, p0 = blockIdx.x * 64;
    stage_x64(x + (size_t)b * CIN * NPOS + p0, t, xt);

    int w = t >> 6, l = t & 63, lr = l & 15, lq = l >> 4;

    bf16x8 ka[2][4], va[2][4];
#pragma unroll
    for (int g = 0; g < 2; ++g)
#pragma unroll
        for (int kk = 0; kk < 4; ++kk) {
            ka[g][kk] = *(const bf16x8*)(wq + (size_t)(128 + w * 32 + g * 16 + lr) * CIN + kk * 32 + lq * 8);
            va[g][kk] = *(const bf16x8*)(wq + (size_t)(256 + w * 32 + g * 16 + lr) * CIN + kk * 32 + lq * 8);
        }
    __syncthreads();

    f32x4 cacc[2][2];
#pragma unroll
    for (int mt = 0; mt < 2; ++mt)
#pragma unroll
        for (int nt = 0; nt < 2; ++nt) cacc[mt][nt] = (f32x4){0.f, 0.f, 0.f, 0.f};
    float sacc[2][4];
#pragma unroll
    for (int g = 0; g < 2; ++g)
#pragma unroll
        for (int r = 0; r < 4; ++r) sacc[g][r] = 0.f;

#pragma unroll
    for (int c4 = 0; c4 < 2; ++c4) {
        bf16x8 xb[2][4];
#pragma unroll
        for (int nt = 0; nt < 2; ++nt)
#pragma unroll
            for (int kk = 0; kk < 4; ++kk)
                xb[nt][kk] = *(const bf16x8*)(&xt[c4 * 32 + nt * 16 + lr][kk * 32 + lq * 8]);

        f32x4 kacc[2][2], vacc[2][2];
#pragma unroll
        for (int g = 0; g < 2; ++g)
#pragma unroll
            for (int nt = 0; nt < 2; ++nt) {
                kacc[g][nt] = (f32x4){0.f, 0.f, 0.f, 0.f};
                vacc[g][nt] = (f32x4){0.f, 0.f, 0.f, 0.f};
            }
#pragma unroll
        for (int g = 0; g < 2; ++g)
#pragma unroll
            for (int nt = 0; nt < 2; ++nt)
#pragma unroll
                for (int kk = 0; kk < 4; ++kk) {
                    kacc[g][nt] = __builtin_amdgcn_mfma_f32_16x16x32_bf16(ka[g][kk], xb[nt][kk], kacc[g][nt], 0, 0, 0);
                    vacc[g][nt] = __builtin_amdgcn_mfma_f32_16x16x32_bf16(va[g][kk], xb[nt][kk], vacc[g][nt], 0, 0, 0);
                }

#pragma unroll
        for (int g = 0; g < 2; ++g)
#pragma unroll
            for (int nt = 0; nt < 2; ++nt)
#pragma unroll
                for (int r = 0; r < 4; ++r) {
                    float e = __expf(kacc[g][nt][r]);
                    sacc[g][r] += e;
                    kb[w][g * 16 + lq * 4 + r][nt * 16 + lr] = f2b(e);
                    vb[w][g * 16 + lq * 4 + r][nt * 16 + lr] = f2b(vacc[g][nt][r]);
                }
        __syncthreads();

        bf16x8 ak[2], av[2];
#pragma unroll
        for (int mt = 0; mt < 2; ++mt) ak[mt] = *(const bf16x8*)(&kb[w][mt * 16 + lr][lq * 8]);
#pragma unroll
        for (int nt = 0; nt < 2; ++nt) av[nt] = *(const bf16x8*)(&vb[w][nt * 16 + lr][lq * 8]);
#pragma unroll
        for (int mt = 0; mt < 2; ++mt)
#pragma unroll
            for (int nt = 0; nt < 2; ++nt)
                cacc[mt][nt] = __builtin_amdgcn_mfma_f32_16x16x32_bf16(ak[mt], av[nt], cacc[mt][nt], 0, 0, 0);
        __syncthreads();
    }

#pragma unroll
    for (int mt = 0; mt < 2; ++mt)
#pragma unroll
        for (int nt = 0; nt < 2; ++nt)
#pragma unroll
            for (int r = 0; r < 4; ++r)
                atomicAdd(&ctx[((size_t)(b * 4 + w) * 32 + mt * 16 + lq * 4 + r) * 32 + nt * 16 + lr],
                          cacc[mt][nt][r]);

#pragma unroll
    for (int g = 0; g < 2; ++g)
#pragma unroll
        for (int r = 0; r < 4; ++r) {
            float s = sacc[g][r];
            s += __shfl_xor(s, 1); s += __shfl_xor(s, 2);
            s += __shfl_xor(s, 4); s += __shfl_xor(s, 8);
            if (lr == 0)
                atomicAdd(&kexp[(b * 4 + w) * 32 + g * 16 + lq * 4 + r], s);
        }
}

__global__ __launch_bounds__(256) void k_weff(const float* __restrict__ wo,
                                              const float* __restrict__ ctx,
                                              const float* __restrict__ kexp,
                                              ushort_t* __restrict__ weff) {
    int bh = blockIdx.x, b = bh >> 2, h = bh & 3;
    __shared__ float wos[128][32];
    __shared__ float cs[32][33];
    int t = threadIdx.x;
#pragma unroll
    for (int k = 0; k < 16; ++k) {
        int idx = k * 256 + t; int c = idx >> 5, e = idx & 31;
        wos[c][e] = wo[(size_t)c * HID + h * 32 + e];
    }
#pragma unroll
    for (int k = 0; k < 4; ++k) {
        int idx = k * 256 + t; int d = idx >> 5, e = idx & 31;
        cs[d][e] = ctx[((size_t)bh * 32 + d) * 32 + e];
    }
    __syncthreads();
#pragma unroll
    for (int k = 0; k < 16; ++k) {
        int idx = k * 256 + t; int c = idx >> 5, d = idx & 31;
        float s = 0.f;
#pragma unroll
        for (int e = 0; e < 32; ++e) s += wos[c][e] * cs[d][e];
        float kin = 1.0f / kexp[bh * 32 + d];
        weff[((size_t)b * HID + c) * HID + h * 32 + d] = f2b(s * kin);
    }
}

__global__ __launch_bounds__(256) void k_outf(const float* __restrict__ x,
                                              const ushort_t* __restrict__ wq,
                                              const ushort_t* __restrict__ weff,
                                              const float* __restrict__ bout,
                                              const float* __restrict__ lng,
                                              const float* __restrict__ lnb,
                                              float* __restrict__ out) {
    __shared__ ushort_t buf[64][136];
    __shared__ float redS[4][64], redQ[4][64];
    int t = threadIdx.x, b = blockIdx.y, p0 = blockIdx.x * 64;
    stage_x64(x + (size_t)b * CIN * NPOS + p0, t, buf);

    int w = t >> 6, l = t & 63, lr = l & 15, lq = l >> 4;

    bf16x8 qa[2][4];
#pragma unroll
    for (int g = 0; g < 2; ++g)
#pragma unroll
        for (int kk = 0; kk < 4; ++kk)
            qa[g][kk] = *(const bf16x8*)(wq + (size_t)(w * 32 + g * 16 + lr) * CIN + kk * 32 + lq * 8);
    __syncthreads();

    f32x4 qacc[2][4];
#pragma unroll
    for (int g = 0; g < 2; ++g)
#pragma unroll
        for (int j = 0; j < 4; ++j) qacc[g][j] = (f32x4){0.f, 0.f, 0.f, 0.f};
#pragma unroll
    for (int j = 0; j < 4; ++j) {
        bf16x8 xb[4];
#pragma unroll
        for (int kk = 0; kk < 4; ++kk)
            xb[kk] = *(const bf16x8*)(&buf[j * 16 + lr][kk * 32 + lq * 8]);
#pragma unroll
        for (int g = 0; g < 2; ++g)
#pragma unroll
            for (int kk = 0; kk < 4; ++kk)
                qacc[g][j] = __builtin_amdgcn_mfma_f32_16x16x32_bf16(qa[g][kk], xb[kk], qacc[g][j], 0, 0, 0);
    }
    __syncthreads();

    const float scale = 0.17677669529663687f;
#pragma unroll
    for (int j = 0; j < 4; ++j) {
        float m = -1e30f;
#pragma unroll
        for (int g = 0; g < 2; ++g)
#pragma unroll
            for (int r = 0; r < 4; ++r) m = fmaxf(m, qacc[g][j][r]);
        m = fmaxf(m, __shfl_xor(m, 16));
        m = fmaxf(m, __shfl_xor(m, 32));
        float e[2][4], s = 0.f;
#pragma unroll
        for (int g = 0; g < 2; ++g)
#pragma unroll
            for (int r = 0; r < 4; ++r) { e[g][r] = __expf(qacc[g][j][r] - m); s += e[g][r]; }
        s += __shfl_xor(s, 16);
        s += __shfl_xor(s, 32);
        float inv = scale / s;
#pragma unroll
        for (int g = 0; g < 2; ++g) {
            ushort4 u;
            u.x = f2b(e[g][0] * inv); u.y = f2b(e[g][1] * inv);
            u.z = f2b(e[g][2] * inv); u.w = f2b(e[g][3] * inv);
            *(ushort4*)(&buf[j * 16 + lr][w * 32 + g * 16 + lq * 4]) = u;
        }
    }
    __syncthreads();

    bf16x8 wa[2][4];
#pragma unroll
    for (int g = 0; g < 2; ++g)
#pragma unroll
        for (int kk = 0; kk < 4; ++kk)
            wa[g][kk] = *(const bf16x8*)(weff + ((size_t)b * HID + w * 32 + g * 16 + lr) * HID + kk * 32 + lq * 8);
    f32x4 oacc[2][4];
#pragma unroll
    for (int g = 0; g < 2; ++g)
#pragma unroll
        for (int j = 0; j < 4; ++j) oacc[g][j] = (f32x4){0.f, 0.f, 0.f, 0.f};
#pragma unroll
    for (int j = 0; j < 4; ++j) {
        bf16x8 sb[4];
#pragma unroll
        for (int kk = 0; kk < 4; ++kk)
            sb[kk] = *(const bf16x8*)(&buf[j * 16 + lr][kk * 32 + lq * 8]);
#pragma unroll
        for (int g = 0; g < 2; ++g)
#pragma unroll
            for (int kk = 0; kk < 4; ++kk)
                oacc[g][j] = __builtin_amdgcn_mfma_f32_16x16x32_bf16(wa[g][kk], sb[kk], oacc[g][j], 0, 0, 0);
    }

    float vals[2][4][4];
    float colS[4] = {0.f, 0.f, 0.f, 0.f}, colQ[4] = {0.f, 0.f, 0.f, 0.f};
#pragma unroll
    for (int g = 0; g < 2; ++g)
#pragma unroll
        for (int r = 0; r < 4; ++r) {
            int c = w * 32 + g * 16 + lq * 4 + r;
            float bias = bout[c];
#pragma unroll
            for (int j = 0; j < 4; ++j) {
                float v = oacc[g][j][r] + bias;
                vals[g][j][r] = v;
                colS[j] += v;
                colQ[j] += v * v;
            }
        }
#pragma unroll
    for (int j = 0; j < 4; ++j) {
        colS[j] += __shfl_xor(colS[j], 16); colQ[j] += __shfl_xor(colQ[j], 16);
        colS[j] += __shfl_xor(colS[j], 32); colQ[j] += __shfl_xor(colQ[j], 32);
        if (lq == 0) { redS[w][j * 16 + lr] = colS[j]; redQ[w][j * 16 + lr] = colQ[j]; }
    }
    __syncthreads();

    float mean[4], rstd[4];
#pragma unroll
    for (int j = 0; j < 4; ++j) {
        int col = j * 16 + lr;
        float S = redS[0][col] + redS[1][col] + redS[2][col] + redS[3][col];
        float Q = redQ[0][col] + redQ[1][col] + redQ[2][col] + redQ[3][col];
        float mu = S * (1.f / 128.f);
        float var = Q * (1.f / 128.f) - mu * mu;
        mean[j] = mu;
        rstd[j] = rsqrtf(var + 1e-5f);
    }

#pragma unroll
    for (int g = 0; g < 2; ++g)
#pragma unroll
        for (int r = 0; r < 4; ++r) {
            int c = w * 32 + g * 16 + lq * 4 + r;
            float gg = lng[c], lb = lnb[c];
#pragma unroll
            for (int j = 0; j < 4; ++j)
                out[((size_t)b * HID + c) * NPOS + p0 + j * 16 + lr] =
                    (vals[g][j][r] - mean[j]) * rstd[j] * gg + lb;
        }
}

extern "C" void kernel_launch(void* const* d_in, const int* in_sizes, int n_in,
                              void* d_out, int out_size, void* d_ws, size_t ws_size,
                              hipStream_t stream) {
    const float* x    = (const float*)d_in[0];
    const float* wqkv = (const float*)d_in[1];
    const float* wout = (const float*)d_in[2];
    const float* bout = (const float*)d_in[3];
    const float* lng  = (const float*)d_in[4];
    const float* lnb  = (const float*)d_in[5];
    float* out = (float*)d_out;

    char* ws = (char*)d_ws;

    // new-path workspace layout
    const size_t off_kexp = 0;                     // GA*16*128 f32      = 512 KB
    const size_t off_ctxp = 524288;                // GA*16*4096 f32     = 16 MB
    const size_t off_wqbf = 17301504;              // 49152 bf16         = 96 KB
    const size_t off_weff = 17399808;              // 16*128*128 bf16    = 512 KB
    const size_t off_qt   = 17924096;              // 16*16384*128 bf16  = 64 MB
    const size_t NEED     = 85032960;

    if (ws_size >= NEED) {
        float*    kexp_part = (float*)(ws + off_kexp);
        float*    ctx_part  = (float*)(ws + off_ctxp);
        ushort_t* wq_bf     = (ushort_t*)(ws + off_wqbf);
        ushort_t* weff      = (ushort_t*)(ws + off_weff);
        ushort_t* qt        = (ushort_t*)(ws + off_qt);

        k_cvt<<<dim3(192), dim3(256), 0, stream>>>(wqkv, wq_bf);
        k_ctxsum2<<<dim3(GA, 16), dim3(256), 0, stream>>>(x, wq_bf, kexp_part, ctx_part, qt);
        k_weff2<<<dim3(64), dim3(256), 0, stream>>>(wout, ctx_part, kexp_part, weff);
        k_outf2<<<dim3(NPOS / 64, 16), dim3(256), 0, stream>>>(qt, weff, bout, lng, lnb, out);
    } else {
        // fallback: previous verified path
        float*    kexp  = (float*)ws;
        float*    ctx   = (float*)(ws + 8192);
        ushort_t* wq_bf = (ushort_t*)(ws + 270336);
        ushort_t* weff  = (ushort_t*)(ws + 368640);

        hipMemsetAsync(ws, 0, 270336, stream);

        k_cvt<<<dim3(192), dim3(256), 0, stream>>>(wqkv, wq_bf);
        k_ctxsum<<<dim3(NPOS / 64, 16), dim3(256), 0, stream>>>(x, wq_bf, kexp, ctx);
        k_weff<<<dim3(64), dim3(256), 0, stream>>>(wout, ctx, kexp, weff);
        k_outf<<<dim3(NPOS / 64, 16), dim3(256), 0, stream>>>(x, wq_bf, weff, bout, lng, lnb, out);
    }
}